// Round 1
// baseline (920.764 us; speedup 1.0000x reference)
//
#include <hip/hip_runtime.h>

// Problem constants (from reference): B=2048, K=1024, D=64, C=32
#define KK 1024
#define DD 64
#define CC 32

__device__ __forceinline__ float d2(const float4 a, const float4 b)
{
    const float dx = a.x - b.x;
    const float dy = a.y - b.y;
    const float dz = a.z - b.z;
    const float dw = a.w - b.w;
    return dx * dx + dy * dy + dz * dz + dw * dw;
}

__device__ __forceinline__ void fma4(float4& a, const float w, const float4 v)
{
    a.x += w * v.x;
    a.y += w * v.y;
    a.z += w * v.z;
    a.w += w * v.w;
}

__global__ __launch_bounds__(256, 4) void nw_attn_kernel(
    const float* __restrict__ x,
    const float* __restrict__ keys,
    const float* __restrict__ values,
    const float* __restrict__ gamma,
    float* __restrict__ out)
{
    const int b    = blockIdx.x;
    const int t    = threadIdx.x;
    const int lane = t & 63;
    const int wave = t >> 6;

    __shared__ float  s_w[KK];          // metric -> softmax weights
    __shared__ float4 s_x[DD / 4];      // query row, broadcast-read
    __shared__ float  s_red[8];         // cross-wave max / sum
    __shared__ float4 s_part[4][CC / 4];// per-wave partial output

    const float g = gamma[0];

    const float4* __restrict__ x4 = (const float4*)x + (size_t)b * (DD / 4);
    const float4* __restrict__ k4 = (const float4*)keys + (size_t)b * KK * (DD / 4);
    const float4* __restrict__ v4 = (const float4*)values + (size_t)b * KK * (CC / 4);

    if (t < DD / 4) s_x[t] = x4[t];
    __syncthreads();

    // ---------------- Phase 1: metric[k] = ||x - key_k||^2 ----------------
    // One key per thread: 16 INDEPENDENT float4 loads per key, no cross-lane
    // ops in the loop. x comes from LDS as wave-uniform broadcast reads.
    for (int kt = 0; kt < KK / 256; ++kt) {
        const int key = kt * 256 + t;
        const float4* __restrict__ kr = k4 + (size_t)key * (DD / 4);
        float m0 = 0.f, m1 = 0.f, m2 = 0.f, m3 = 0.f;
        #pragma unroll
        for (int j = 0; j < DD / 4; j += 4) {
            const float4 c0 = kr[j + 0];
            const float4 c1 = kr[j + 1];
            const float4 c2 = kr[j + 2];
            const float4 c3 = kr[j + 3];
            m0 += d2(s_x[j + 0], c0);
            m1 += d2(s_x[j + 1], c1);
            m2 += d2(s_x[j + 2], c2);
            m3 += d2(s_x[j + 3], c3);
        }
        s_w[key] = -g * ((m0 + m1) + (m2 + m3));
    }
    __syncthreads();

    // ---------------- Phase 2: softmax over K in LDS ----------------
    const float v0 = s_w[t];
    const float v1 = s_w[t + 256];
    const float v2 = s_w[t + 512];
    const float v3 = s_w[t + 768];
    float lmax = fmaxf(fmaxf(v0, v1), fmaxf(v2, v3));
    #pragma unroll
    for (int off = 32; off >= 1; off >>= 1)
        lmax = fmaxf(lmax, __shfl_xor(lmax, off));
    if (lane == 0) s_red[wave] = lmax;
    __syncthreads();
    const float bmax = fmaxf(fmaxf(s_red[0], s_red[1]),
                             fmaxf(s_red[2], s_red[3]));

    const float e0 = __expf(v0 - bmax);
    const float e1 = __expf(v1 - bmax);
    const float e2 = __expf(v2 - bmax);
    const float e3 = __expf(v3 - bmax);
    s_w[t]       = e0;
    s_w[t + 256] = e1;
    s_w[t + 512] = e2;
    s_w[t + 768] = e3;
    float lsum = e0 + e1 + e2 + e3;
    #pragma unroll
    for (int off = 32; off >= 1; off >>= 1)
        lsum += __shfl_xor(lsum, off);
    if (lane == 0) s_red[4 + wave] = lsum;
    __syncthreads();
    const float inv_sum = 1.0f / (s_red[4] + s_red[5] + s_red[6] + s_red[7]);

    // ---------------- Phase 3: pred[c] = sum_k w[k] * values[k][c] ----------------
    // One key per thread: 8 INDEPENDENT float4 loads per key; full C=32
    // accumulated in registers; single butterfly reduce at the end.
    float4 a0 = make_float4(0.f, 0.f, 0.f, 0.f);
    float4 a1 = a0, a2 = a0, a3 = a0, a4 = a0, a5 = a0, a6 = a0, a7 = a0;

    for (int kt = 0; kt < KK / 256; ++kt) {
        const int key = kt * 256 + t;
        const float w = s_w[key];
        const float4* __restrict__ vr = v4 + (size_t)key * (CC / 4);
        const float4 b0 = vr[0];
        const float4 b1 = vr[1];
        const float4 b2 = vr[2];
        const float4 b3 = vr[3];
        const float4 b4 = vr[4];
        const float4 b5 = vr[5];
        const float4 b6 = vr[6];
        const float4 b7 = vr[7];
        fma4(a0, w, b0);
        fma4(a1, w, b1);
        fma4(a2, w, b2);
        fma4(a3, w, b3);
        fma4(a4, w, b4);
        fma4(a5, w, b5);
        fma4(a6, w, b6);
        fma4(a7, w, b7);
    }

    // Reduce the 32 accumulated c-values across the 64 lanes of the wave.
    #define RED4(v) do { \
        v.x += __shfl_xor(v.x, off); \
        v.y += __shfl_xor(v.y, off); \
        v.z += __shfl_xor(v.z, off); \
        v.w += __shfl_xor(v.w, off); \
    } while (0)

    #pragma unroll
    for (int s = 0; s < 6; ++s) {
        const int off = 1 << s;
        RED4(a0); RED4(a1); RED4(a2); RED4(a3);
        RED4(a4); RED4(a5); RED4(a6); RED4(a7);
    }
    #undef RED4

    if (lane == 0) {
        s_part[wave][0] = a0;
        s_part[wave][1] = a1;
        s_part[wave][2] = a2;
        s_part[wave][3] = a3;
        s_part[wave][4] = a4;
        s_part[wave][5] = a5;
        s_part[wave][6] = a6;
        s_part[wave][7] = a7;
    }
    __syncthreads();

    if (t < CC) {
        const float* p = (const float*)s_part;   // [wave][c], 32 floats per wave
        const float r = (p[t] + p[32 + t] + p[64 + t] + p[96 + t]) * inv_sum;
        out[(size_t)b * CC + t] = r;
    }
}

extern "C" void kernel_launch(void* const* d_in, const int* in_sizes, int n_in,
                              void* d_out, int out_size, void* d_ws, size_t ws_size,
                              hipStream_t stream) {
    const float* x      = (const float*)d_in[0];
    const float* keys   = (const float*)d_in[1];
    const float* values = (const float*)d_in[2];
    const float* gamma  = (const float*)d_in[3];
    float* out = (float*)d_out;

    const int b = in_sizes[0] / DD;   // 2048
    nw_attn_kernel<<<dim3(b), dim3(256), 0, stream>>>(x, keys, values, gamma, out);
}